// Round 5
// baseline (387.046 us; speedup 1.0000x reference)
//
#include <hip/hip_runtime.h>
#include <hip/hip_fp16.h>

// Trilinear feature interpolation on a regular 65^3 vertex grid.
// R=64, SCALE=1.05, C=64, N=500000.
//
// R5 pipeline (all on `stream`):
//   memset  : zero 512-bin histogram (in d_ws)
//   K1      : convert feats f32->f16 into d_ws  +  histogram points into
//             512 spatial superblocks (8^3 cells each)         [fused]
//   K2      : exclusive scan of the 512 bins -> cursor          [1 block]
//   K3      : scatter 16B point records {x,y,z,orig} into sorted order
//   K4      : trilerp gather in sorted order, bijective XCD-chunked block
//             swizzle -> each XCD walks a contiguous ~4.4MB slab of the
//             35MB fp16 table with <1MB active working set -> L2 hits.
// Rationale: R4 measured 225MB L2-miss gather refills (45% miss) as the
// dominant reducible traffic; sorting makes those misses non-compulsory.

#define GRID_R     64
#define GRID_R1    65
#define NCHAN      64
#define NVERT      (GRID_R1 * GRID_R1 * GRID_R1)    // 274625
#define FEAT_ELEMS ((size_t)NVERT * NCHAN)          // 17,576,000 floats
#define NBINS      512                               // 8x8x8 superblocks

typedef float    f32x4 __attribute__((ext_vector_type(4)));
typedef _Float16 f16x8 __attribute__((ext_vector_type(8)));

// ---- shared cell computation (must be identical in hist/scatter/main) ----
__device__ __forceinline__ void cell_of(float px, float py, float pz,
                                        int& ci, int& cj, int& ck) {
    float x = (px / 2.1f + 0.5f) * 64.0f;
    float y = (py / 2.1f + 0.5f) * 64.0f;
    float z = (pz / 2.1f + 0.5f) * 64.0f;
    x = fminf(fmaxf(x, 0.0f), 64.0f);
    y = fminf(fmaxf(y, 0.0f), 64.0f);
    z = fminf(fmaxf(z, 0.0f), 64.0f);
    ci = min((int)x, GRID_R - 1);
    cj = min((int)y, GRID_R - 1);
    ck = min((int)z, GRID_R - 1);
}

__device__ __forceinline__ int sbin_of(int ci, int cj, int ck) {
    return ((ci >> 3) << 6) | ((cj >> 3) << 3) | (ck >> 3);
}

// ---- K1: feats f32->f16 (streaming) + point histogram (fused) ----
__global__ __launch_bounds__(256) void convert_hist_kernel(
    const f32x4* __restrict__ in,   // feats as f32x4, 2 per output f16x8
    f16x8* __restrict__ outF,
    const float* __restrict__ pos,
    int* __restrict__ hist,
    int n8, int n)
{
    int i = blockIdx.x * 256 + threadIdx.x;
    if (i < n8) {
        f32x4 a = in[2 * i];
        f32x4 b = in[2 * i + 1];
        f16x8 h;
        h[0] = (_Float16)a.x; h[1] = (_Float16)a.y;
        h[2] = (_Float16)a.z; h[3] = (_Float16)a.w;
        h[4] = (_Float16)b.x; h[5] = (_Float16)b.y;
        h[6] = (_Float16)b.z; h[7] = (_Float16)b.w;
        __builtin_nontemporal_store(h, &outF[i]);
    }
    if (i < n) {
        int ci, cj, ck;
        cell_of(pos[i * 3], pos[i * 3 + 1], pos[i * 3 + 2], ci, cj, ck);
        atomicAdd(&hist[sbin_of(ci, cj, ck)], 1);
    }
}

// ---- K2: exclusive scan of 512 bins -> cursor (single block) ----
__global__ __launch_bounds__(NBINS) void scan_kernel(
    const int* __restrict__ hist, int* __restrict__ cursor)
{
    __shared__ int s[NBINS];
    const int t = threadIdx.x;
    int own = hist[t];
    s[t] = own;
    __syncthreads();
    for (int off = 1; off < NBINS; off <<= 1) {
        int v = (t >= off) ? s[t - off] : 0;
        __syncthreads();
        s[t] += v;
        __syncthreads();
    }
    cursor[t] = s[t] - own;   // exclusive prefix
}

// ---- K3: scatter sorted point records {px,py,pz,orig_idx} ----
__global__ __launch_bounds__(256) void scatter_kernel(
    const float* __restrict__ pos,
    int* __restrict__ cursor,
    f32x4* __restrict__ records,
    int n)
{
    int i = blockIdx.x * 256 + threadIdx.x;
    if (i >= n) return;
    float px = pos[i * 3], py = pos[i * 3 + 1], pz = pos[i * 3 + 2];
    int ci, cj, ck;
    cell_of(px, py, pz, ci, cj, ck);
    int slot = atomicAdd(&cursor[sbin_of(ci, cj, ck)], 1);
    f32x4 r = {px, py, pz, __int_as_float(i)};
    records[slot] = r;
}

// ---- K4: sorted trilerp gather (fp16 table), XCD-chunked swizzle ----
__global__ __launch_bounds__(256) void trilerp_sorted_kernel(
    const f32x4* __restrict__ records, // [n] {x,y,z,orig}
    const f16x8* __restrict__ feats,   // [65^3, 8] f16x8 (64 ch per row)
    f32x4* __restrict__ out4,          // [n,16] f32x4
    int n, int nwg)
{
    // Bijective XCD-chunk swizzle (m204): XCD x gets a contiguous range of
    // virtual blocks -> contiguous range of the sorted points -> contiguous
    // slab of the feature table resident in that XCD's L2.
    const int o  = blockIdx.x;
    const int x  = o & 7, oo = o >> 3;
    const int q  = nwg >> 3, r = nwg & 7;
    const int vb = (x < r ? x * (q + 1) : r * (q + 1) + (x - r) * q) + oo;

    const int slot = vb * 32 + (threadIdx.x >> 3);  // 8 lanes per point
    if (slot >= n) return;
    const int sub = threadIdx.x & 7;

    const f32x4 rec = records[slot];   // 16B broadcast within the 8-lane group
    const float px = rec.x, py = rec.y, pz = rec.z;
    const int orig = __float_as_int(rec.w);

    int ci, cj, ck;
    cell_of(px, py, pz, ci, cj, ck);

    // Vertex coords: v(a) = (a * 2^-6 - 0.5) * 2.1 (bit-matches numpy table)
    const float INV_GS = 64.0f / 2.1f;
    float vx0 = ((float)ci       * 0.015625f - 0.5f) * 2.1f;
    float vx1 = ((float)(ci + 1) * 0.015625f - 0.5f) * 2.1f;
    float vy0 = ((float)cj       * 0.015625f - 0.5f) * 2.1f;
    float vy1 = ((float)(cj + 1) * 0.015625f - 0.5f) * 2.1f;
    float vz0 = ((float)ck       * 0.015625f - 0.5f) * 2.1f;
    float vz1 = ((float)(ck + 1) * 0.015625f - 0.5f) * 2.1f;

    // Corner (dx,dy,dz) weighted by distance to the OPPOSITE vertex.
    float wx1 = fabsf(px - vx0) * INV_GS;
    float wx0 = fabsf(px - vx1) * INV_GS;
    float wy1 = fabsf(py - vy0) * INV_GS;
    float wy0 = fabsf(py - vy1) * INV_GS;
    float wz1 = fabsf(pz - vz0) * INV_GS;
    float wz0 = fabsf(pz - vz1) * INV_GS;

    const int RS = NCHAN / 8;                 // 8 f16x8 units per row
    const int SY = GRID_R1 * RS;
    const int SX = GRID_R1 * GRID_R1 * RS;
    int base = ((ci * GRID_R1 + cj) * GRID_R1 + ck) * RS + sub;

    f16x8 f000 = feats[base];
    f16x8 f001 = feats[base + RS];
    f16x8 f010 = feats[base + SY];
    f16x8 f011 = feats[base + SY + RS];
    f16x8 f100 = feats[base + SX];
    f16x8 f101 = feats[base + SX + RS];
    f16x8 f110 = feats[base + SX + SY];
    f16x8 f111 = feats[base + SX + SY + RS];

    float w000 = wx0 * wy0 * wz0, w001 = wx0 * wy0 * wz1;
    float w010 = wx0 * wy1 * wz0, w011 = wx0 * wy1 * wz1;
    float w100 = wx1 * wy0 * wz0, w101 = wx1 * wy0 * wz1;
    float w110 = wx1 * wy1 * wz0, w111 = wx1 * wy1 * wz1;

    f32x4 acc0 = {0.f, 0.f, 0.f, 0.f};
    f32x4 acc1 = {0.f, 0.f, 0.f, 0.f};
#define ACCUM(F, W)                                                  \
    { acc0.x += (float)F[0] * W; acc0.y += (float)F[1] * W;          \
      acc0.z += (float)F[2] * W; acc0.w += (float)F[3] * W;          \
      acc1.x += (float)F[4] * W; acc1.y += (float)F[5] * W;          \
      acc1.z += (float)F[6] * W; acc1.w += (float)F[7] * W; }
    ACCUM(f000, w000) ACCUM(f001, w001) ACCUM(f010, w010) ACCUM(f011, w011)
    ACCUM(f100, w100) ACCUM(f101, w101) ACCUM(f110, w110) ACCUM(f111, w111)
#undef ACCUM

    // Scattered-but-contiguous 256B per point, write-once: nontemporal.
    __builtin_nontemporal_store(acc0, &out4[orig * 16 + sub * 2]);
    __builtin_nontemporal_store(acc1, &out4[orig * 16 + sub * 2 + 1]);
}

// ---- fallback: R4 unsorted fp16 gather ----
__global__ __launch_bounds__(256) void trilerp_f16_kernel(
    const float* __restrict__ pos,
    const f16x8* __restrict__ feats,
    f32x4* __restrict__ out4,
    int n)
{
    const int tid = blockIdx.x * 256 + threadIdx.x;
    const int pt  = tid >> 3;
    if (pt >= n) return;
    const int sub = tid & 7;

    const float px = pos[pt * 3], py = pos[pt * 3 + 1], pz = pos[pt * 3 + 2];
    int ci, cj, ck;
    cell_of(px, py, pz, ci, cj, ck);

    const float INV_GS = 64.0f / 2.1f;
    float vx0 = ((float)ci       * 0.015625f - 0.5f) * 2.1f;
    float vx1 = ((float)(ci + 1) * 0.015625f - 0.5f) * 2.1f;
    float vy0 = ((float)cj       * 0.015625f - 0.5f) * 2.1f;
    float vy1 = ((float)(cj + 1) * 0.015625f - 0.5f) * 2.1f;
    float vz0 = ((float)ck       * 0.015625f - 0.5f) * 2.1f;
    float vz1 = ((float)(ck + 1) * 0.015625f - 0.5f) * 2.1f;

    float wx1 = fabsf(px - vx0) * INV_GS;
    float wx0 = fabsf(px - vx1) * INV_GS;
    float wy1 = fabsf(py - vy0) * INV_GS;
    float wy0 = fabsf(py - vy1) * INV_GS;
    float wz1 = fabsf(pz - vz0) * INV_GS;
    float wz0 = fabsf(pz - vz1) * INV_GS;

    const int RS = NCHAN / 8, SY = GRID_R1 * RS, SX = GRID_R1 * GRID_R1 * RS;
    int base = ((ci * GRID_R1 + cj) * GRID_R1 + ck) * RS + sub;

    f16x8 f000 = feats[base];
    f16x8 f001 = feats[base + RS];
    f16x8 f010 = feats[base + SY];
    f16x8 f011 = feats[base + SY + RS];
    f16x8 f100 = feats[base + SX];
    f16x8 f101 = feats[base + SX + RS];
    f16x8 f110 = feats[base + SX + SY];
    f16x8 f111 = feats[base + SX + SY + RS];

    float w000 = wx0 * wy0 * wz0, w001 = wx0 * wy0 * wz1;
    float w010 = wx0 * wy1 * wz0, w011 = wx0 * wy1 * wz1;
    float w100 = wx1 * wy0 * wz0, w101 = wx1 * wy0 * wz1;
    float w110 = wx1 * wy1 * wz0, w111 = wx1 * wy1 * wz1;

    f32x4 acc0 = {0.f, 0.f, 0.f, 0.f};
    f32x4 acc1 = {0.f, 0.f, 0.f, 0.f};
#define ACCUM(F, W)                                                  \
    { acc0.x += (float)F[0] * W; acc0.y += (float)F[1] * W;          \
      acc0.z += (float)F[2] * W; acc0.w += (float)F[3] * W;          \
      acc1.x += (float)F[4] * W; acc1.y += (float)F[5] * W;          \
      acc1.z += (float)F[6] * W; acc1.w += (float)F[7] * W; }
    ACCUM(f000, w000) ACCUM(f001, w001) ACCUM(f010, w010) ACCUM(f011, w011)
    ACCUM(f100, w100) ACCUM(f101, w101) ACCUM(f110, w110) ACCUM(f111, w111)
#undef ACCUM

    __builtin_nontemporal_store(acc0, &out4[pt * 16 + sub * 2]);
    __builtin_nontemporal_store(acc1, &out4[pt * 16 + sub * 2 + 1]);
}

// ---- fallback: R3 direct f32 gather ----
__global__ __launch_bounds__(256) void trilerp_f32_kernel(
    const float* __restrict__ pos,
    const f32x4* __restrict__ feats4,
    f32x4* __restrict__ out4,
    int n)
{
    const int tid = blockIdx.x * 256 + threadIdx.x;
    const int pt  = tid >> 4;
    if (pt >= n) return;
    const int sub = tid & 15;

    const float px = pos[pt * 3], py = pos[pt * 3 + 1], pz = pos[pt * 3 + 2];
    int ci, cj, ck;
    cell_of(px, py, pz, ci, cj, ck);

    const float INV_GS = 64.0f / 2.1f;
    float vx0 = ((float)ci       * 0.015625f - 0.5f) * 2.1f;
    float vx1 = ((float)(ci + 1) * 0.015625f - 0.5f) * 2.1f;
    float vy0 = ((float)cj       * 0.015625f - 0.5f) * 2.1f;
    float vy1 = ((float)(cj + 1) * 0.015625f - 0.5f) * 2.1f;
    float vz0 = ((float)ck       * 0.015625f - 0.5f) * 2.1f;
    float vz1 = ((float)(ck + 1) * 0.015625f - 0.5f) * 2.1f;

    float wx1 = fabsf(px - vx0) * INV_GS;
    float wx0 = fabsf(px - vx1) * INV_GS;
    float wy1 = fabsf(py - vy0) * INV_GS;
    float wy0 = fabsf(py - vy1) * INV_GS;
    float wz1 = fabsf(pz - vz0) * INV_GS;
    float wz0 = fabsf(pz - vz1) * INV_GS;

    const int RS = 16, SY = GRID_R1 * RS, SX = GRID_R1 * GRID_R1 * RS;
    int base = ((ci * GRID_R1 + cj) * GRID_R1 + ck) * RS + sub;

    f32x4 f000 = feats4[base];
    f32x4 f001 = feats4[base + RS];
    f32x4 f010 = feats4[base + SY];
    f32x4 f011 = feats4[base + SY + RS];
    f32x4 f100 = feats4[base + SX];
    f32x4 f101 = feats4[base + SX + RS];
    f32x4 f110 = feats4[base + SX + SY];
    f32x4 f111 = feats4[base + SX + SY + RS];

    float w000 = wx0 * wy0 * wz0, w001 = wx0 * wy0 * wz1;
    float w010 = wx0 * wy1 * wz0, w011 = wx0 * wy1 * wz1;
    float w100 = wx1 * wy0 * wz0, w101 = wx1 * wy0 * wz1;
    float w110 = wx1 * wy1 * wz0, w111 = wx1 * wy1 * wz1;

    f32x4 acc = f000 * w000 + f001 * w001 + f010 * w010 + f011 * w011
              + f100 * w100 + f101 * w101 + f110 * w110 + f111 * w111;

    __builtin_nontemporal_store(acc, &out4[pt * 16 + sub]);
}

extern "C" void kernel_launch(void* const* d_in, const int* in_sizes, int n_in,
                              void* d_out, int out_size, void* d_ws, size_t ws_size,
                              hipStream_t stream) {
    const float* pos   = (const float*)d_in[0];
    const float* feats = (const float*)d_in[1];
    // d_in[2] (vertices) and d_in[3] (grid_indices) recomputed analytically.
    f32x4* out4 = (f32x4*)d_out;

    const int n  = in_sizes[0] / 3;                 // 500000
    const int n8 = (int)(FEAT_ELEMS / 8);           // 2,197,000

    // d_ws layout
    const size_t featBytes = FEAT_ELEMS * sizeof(_Float16);      // 35,152,000
    const size_t offF = 0;
    const size_t offR = (featBytes + 127) & ~(size_t)127;        // records
    const size_t offH = offR + (size_t)n * 16;                   // hist
    const size_t offC = offH + NBINS * sizeof(int);              // cursor
    const size_t needSorted = offC + NBINS * sizeof(int);

    if (ws_size >= needSorted) {
        char* ws = (char*)d_ws;
        f16x8* feats16 = (f16x8*)(ws + offF);
        f32x4* records = (f32x4*)(ws + offR);
        int*   hist    = (int*)(ws + offH);
        int*   cursor  = (int*)(ws + offC);

        hipMemsetAsync(hist, 0, NBINS * sizeof(int), stream);

        const int k1_blocks = (n8 + 255) / 256;     // covers both n8 and n
        convert_hist_kernel<<<k1_blocks, 256, 0, stream>>>(
            (const f32x4*)feats, feats16, pos, hist, n8, n);

        scan_kernel<<<1, NBINS, 0, stream>>>(hist, cursor);

        scatter_kernel<<<(n + 255) / 256, 256, 0, stream>>>(
            pos, cursor, records, n);

        const int nwg = (n + 31) / 32;              // 32 points per block
        trilerp_sorted_kernel<<<nwg, 256, 0, stream>>>(
            records, feats16, out4, n, nwg);
    } else if (ws_size >= featBytes) {
        f16x8* feats16 = (f16x8*)d_ws;
        convert_hist_kernel<<<(n8 + 255) / 256, 256, 0, stream>>>(
            (const f32x4*)feats, feats16, nullptr, nullptr, n8, 0);
        const long long total = (long long)n * 8;
        trilerp_f16_kernel<<<(int)((total + 255) / 256), 256, 0, stream>>>(
            pos, feats16, out4, n);
    } else {
        const long long total = (long long)n * 16;
        trilerp_f32_kernel<<<(int)((total + 255) / 256), 256, 0, stream>>>(
            pos, (const f32x4*)feats, out4, n);
    }
}

// Round 6
// 127.445 us; speedup vs baseline: 3.0370x; 3.0370x over previous
//
#include <hip/hip_runtime.h>
#include <hip/hip_fp16.h>

// Trilinear feature interpolation on a regular 65^3 vertex grid.
// R=64, SCALE=1.05, C=64, N=500000.
//
// R6 pipeline (all on `stream`):
//   memset : zero 64x512 replicated histogram
//   K1     : feats f32->f16 convert (streaming)  +  point histogram into
//            512 spatial bins REPLICATED 64x (rep = blockIdx&63) to kill
//            the atomic contention that cost R5 163us (500k atomics on 512
//            addresses -> 15 collisions/addr on 32k addresses).
//   K2     : scan: per-bin sequential prefix over 64 reps + block scan over
//            512 bins -> cursor[rep][bin] (single 512-thread block)
//   K3     : scatter 16B records {x,y,z,orig} via cursor[rep][bin] atomics
//   K4     : trilerp gather in bin-sorted order + bijective XCD-chunk swizzle
//            -> each XCD walks a contiguous slab of the 35MB fp16 table.

#define GRID_R     64
#define GRID_R1    65
#define NCHAN      64
#define NVERT      (GRID_R1 * GRID_R1 * GRID_R1)    // 274625
#define FEAT_ELEMS ((size_t)NVERT * NCHAN)          // 17,576,000 floats
#define NBINS      512                              // 8x8x8 superblocks
#define REPS       64                               // histogram replication

typedef float    f32x4 __attribute__((ext_vector_type(4)));
typedef _Float16 f16x8 __attribute__((ext_vector_type(8)));

__device__ __forceinline__ void cell_of(float px, float py, float pz,
                                        int& ci, int& cj, int& ck) {
    float x = (px / 2.1f + 0.5f) * 64.0f;
    float y = (py / 2.1f + 0.5f) * 64.0f;
    float z = (pz / 2.1f + 0.5f) * 64.0f;
    x = fminf(fmaxf(x, 0.0f), 64.0f);
    y = fminf(fmaxf(y, 0.0f), 64.0f);
    z = fminf(fmaxf(z, 0.0f), 64.0f);
    ci = min((int)x, GRID_R - 1);
    cj = min((int)y, GRID_R - 1);
    ck = min((int)z, GRID_R - 1);
}

__device__ __forceinline__ int sbin_of(int ci, int cj, int ck) {
    return ((ci >> 3) << 6) | ((cj >> 3) << 3) | (ck >> 3);
}

// ---- K1: feats f32->f16 (streaming) + replicated point histogram ----
__global__ __launch_bounds__(256) void convert_hist_kernel(
    const f32x4* __restrict__ in,
    f16x8* __restrict__ outF,
    const float* __restrict__ pos,
    int* __restrict__ hist,          // [REPS][NBINS]
    int n8, int n)
{
    int i = blockIdx.x * 256 + threadIdx.x;
    if (i < n8) {
        f32x4 a = __builtin_nontemporal_load(&in[2 * i]);
        f32x4 b = __builtin_nontemporal_load(&in[2 * i + 1]);
        f16x8 h;
        h[0] = (_Float16)a.x; h[1] = (_Float16)a.y;
        h[2] = (_Float16)a.z; h[3] = (_Float16)a.w;
        h[4] = (_Float16)b.x; h[5] = (_Float16)b.y;
        h[6] = (_Float16)b.z; h[7] = (_Float16)b.w;
        __builtin_nontemporal_store(h, &outF[i]);
    }
    if (i < n) {
        int ci, cj, ck;
        cell_of(pos[i * 3], pos[i * 3 + 1], pos[i * 3 + 2], ci, cj, ck);
        const int rep = blockIdx.x & (REPS - 1);   // must match scatter_kernel
        atomicAdd(&hist[rep * NBINS + sbin_of(ci, cj, ck)], 1);
    }
}

// ---- K2: cursor[rep][bin] = binBase[bin] + prefix over reps ----
__global__ __launch_bounds__(NBINS) void scan_kernel(
    const int* __restrict__ hist,    // [REPS][NBINS]
    int* __restrict__ cursor)        // [REPS][NBINS]
{
    __shared__ int s[NBINS];
    const int t = threadIdx.x;       // bin id
    int pre[REPS];
    int tot = 0;
#pragma unroll
    for (int r = 0; r < REPS; ++r) { pre[r] = tot; tot += hist[r * NBINS + t]; }
    s[t] = tot;
    __syncthreads();
    for (int off = 1; off < NBINS; off <<= 1) {
        int v = (t >= off) ? s[t - off] : 0;
        __syncthreads();
        s[t] += v;
        __syncthreads();
    }
    const int base = s[t] - tot;     // exclusive over bins
#pragma unroll
    for (int r = 0; r < REPS; ++r) cursor[r * NBINS + t] = base + pre[r];
}

// ---- K3: scatter sorted point records {px,py,pz,orig_idx} ----
__global__ __launch_bounds__(256) void scatter_kernel(
    const float* __restrict__ pos,
    int* __restrict__ cursor,        // [REPS][NBINS]
    f32x4* __restrict__ records,
    int n)
{
    int i = blockIdx.x * 256 + threadIdx.x;
    if (i >= n) return;
    float px = pos[i * 3], py = pos[i * 3 + 1], pz = pos[i * 3 + 2];
    int ci, cj, ck;
    cell_of(px, py, pz, ci, cj, ck);
    const int rep = blockIdx.x & (REPS - 1);       // must match K1
    int slot = atomicAdd(&cursor[rep * NBINS + sbin_of(ci, cj, ck)], 1);
    f32x4 r = {px, py, pz, __int_as_float(i)};
    __builtin_nontemporal_store(r, &records[slot]);
}

// ---- K4: sorted trilerp gather (fp16 table), XCD-chunked swizzle ----
__global__ __launch_bounds__(256) void trilerp_sorted_kernel(
    const f32x4* __restrict__ records,
    const f16x8* __restrict__ feats,
    f32x4* __restrict__ out4,
    int n, int nwg)
{
    const int o  = blockIdx.x;
    const int x  = o & 7, oo = o >> 3;
    const int q  = nwg >> 3, r = nwg & 7;
    const int vb = (x < r ? x * (q + 1) : r * (q + 1) + (x - r) * q) + oo;

    const int slot = vb * 32 + (threadIdx.x >> 3);  // 8 lanes per point
    if (slot >= n) return;
    const int sub = threadIdx.x & 7;

    const f32x4 rec = records[slot];
    const float px = rec.x, py = rec.y, pz = rec.z;
    const int orig = __float_as_int(rec.w);

    int ci, cj, ck;
    cell_of(px, py, pz, ci, cj, ck);

    const float INV_GS = 64.0f / 2.1f;
    float vx0 = ((float)ci       * 0.015625f - 0.5f) * 2.1f;
    float vx1 = ((float)(ci + 1) * 0.015625f - 0.5f) * 2.1f;
    float vy0 = ((float)cj       * 0.015625f - 0.5f) * 2.1f;
    float vy1 = ((float)(cj + 1) * 0.015625f - 0.5f) * 2.1f;
    float vz0 = ((float)ck       * 0.015625f - 0.5f) * 2.1f;
    float vz1 = ((float)(ck + 1) * 0.015625f - 0.5f) * 2.1f;

    float wx1 = fabsf(px - vx0) * INV_GS;
    float wx0 = fabsf(px - vx1) * INV_GS;
    float wy1 = fabsf(py - vy0) * INV_GS;
    float wy0 = fabsf(py - vy1) * INV_GS;
    float wz1 = fabsf(pz - vz0) * INV_GS;
    float wz0 = fabsf(pz - vz1) * INV_GS;

    const int RS = NCHAN / 8;
    const int SY = GRID_R1 * RS;
    const int SX = GRID_R1 * GRID_R1 * RS;
    int base = ((ci * GRID_R1 + cj) * GRID_R1 + ck) * RS + sub;

    f16x8 f000 = feats[base];
    f16x8 f001 = feats[base + RS];
    f16x8 f010 = feats[base + SY];
    f16x8 f011 = feats[base + SY + RS];
    f16x8 f100 = feats[base + SX];
    f16x8 f101 = feats[base + SX + RS];
    f16x8 f110 = feats[base + SX + SY];
    f16x8 f111 = feats[base + SX + SY + RS];

    float w000 = wx0 * wy0 * wz0, w001 = wx0 * wy0 * wz1;
    float w010 = wx0 * wy1 * wz0, w011 = wx0 * wy1 * wz1;
    float w100 = wx1 * wy0 * wz0, w101 = wx1 * wy0 * wz1;
    float w110 = wx1 * wy1 * wz0, w111 = wx1 * wy1 * wz1;

    f32x4 acc0 = {0.f, 0.f, 0.f, 0.f};
    f32x4 acc1 = {0.f, 0.f, 0.f, 0.f};
#define ACCUM(F, W)                                                  \
    { acc0.x += (float)F[0] * W; acc0.y += (float)F[1] * W;          \
      acc0.z += (float)F[2] * W; acc0.w += (float)F[3] * W;          \
      acc1.x += (float)F[4] * W; acc1.y += (float)F[5] * W;          \
      acc1.z += (float)F[6] * W; acc1.w += (float)F[7] * W; }
    ACCUM(f000, w000) ACCUM(f001, w001) ACCUM(f010, w010) ACCUM(f011, w011)
    ACCUM(f100, w100) ACCUM(f101, w101) ACCUM(f110, w110) ACCUM(f111, w111)
#undef ACCUM

    __builtin_nontemporal_store(acc0, &out4[orig * 16 + sub * 2]);
    __builtin_nontemporal_store(acc1, &out4[orig * 16 + sub * 2 + 1]);
}

// ---- fallback: R4 unsorted fp16 gather ----
__global__ __launch_bounds__(256) void trilerp_f16_kernel(
    const float* __restrict__ pos,
    const f16x8* __restrict__ feats,
    f32x4* __restrict__ out4,
    int n)
{
    const int tid = blockIdx.x * 256 + threadIdx.x;
    const int pt  = tid >> 3;
    if (pt >= n) return;
    const int sub = tid & 7;

    const float px = pos[pt * 3], py = pos[pt * 3 + 1], pz = pos[pt * 3 + 2];
    int ci, cj, ck;
    cell_of(px, py, pz, ci, cj, ck);

    const float INV_GS = 64.0f / 2.1f;
    float vx0 = ((float)ci       * 0.015625f - 0.5f) * 2.1f;
    float vx1 = ((float)(ci + 1) * 0.015625f - 0.5f) * 2.1f;
    float vy0 = ((float)cj       * 0.015625f - 0.5f) * 2.1f;
    float vy1 = ((float)(cj + 1) * 0.015625f - 0.5f) * 2.1f;
    float vz0 = ((float)ck       * 0.015625f - 0.5f) * 2.1f;
    float vz1 = ((float)(ck + 1) * 0.015625f - 0.5f) * 2.1f;

    float wx1 = fabsf(px - vx0) * INV_GS;
    float wx0 = fabsf(px - vx1) * INV_GS;
    float wy1 = fabsf(py - vy0) * INV_GS;
    float wy0 = fabsf(py - vy1) * INV_GS;
    float wz1 = fabsf(pz - vz0) * INV_GS;
    float wz0 = fabsf(pz - vz1) * INV_GS;

    const int RS = NCHAN / 8, SY = GRID_R1 * RS, SX = GRID_R1 * GRID_R1 * RS;
    int base = ((ci * GRID_R1 + cj) * GRID_R1 + ck) * RS + sub;

    f16x8 f000 = feats[base];
    f16x8 f001 = feats[base + RS];
    f16x8 f010 = feats[base + SY];
    f16x8 f011 = feats[base + SY + RS];
    f16x8 f100 = feats[base + SX];
    f16x8 f101 = feats[base + SX + RS];
    f16x8 f110 = feats[base + SX + SY];
    f16x8 f111 = feats[base + SX + SY + RS];

    float w000 = wx0 * wy0 * wz0, w001 = wx0 * wy0 * wz1;
    float w010 = wx0 * wy1 * wz0, w011 = wx0 * wy1 * wz1;
    float w100 = wx1 * wy0 * wz0, w101 = wx1 * wy0 * wz1;
    float w110 = wx1 * wy1 * wz0, w111 = wx1 * wy1 * wz1;

    f32x4 acc0 = {0.f, 0.f, 0.f, 0.f};
    f32x4 acc1 = {0.f, 0.f, 0.f, 0.f};
#define ACCUM(F, W)                                                  \
    { acc0.x += (float)F[0] * W; acc0.y += (float)F[1] * W;          \
      acc0.z += (float)F[2] * W; acc0.w += (float)F[3] * W;          \
      acc1.x += (float)F[4] * W; acc1.y += (float)F[5] * W;          \
      acc1.z += (float)F[6] * W; acc1.w += (float)F[7] * W; }
    ACCUM(f000, w000) ACCUM(f001, w001) ACCUM(f010, w010) ACCUM(f011, w011)
    ACCUM(f100, w100) ACCUM(f101, w101) ACCUM(f110, w110) ACCUM(f111, w111)
#undef ACCUM

    __builtin_nontemporal_store(acc0, &out4[pt * 16 + sub * 2]);
    __builtin_nontemporal_store(acc1, &out4[pt * 16 + sub * 2 + 1]);
}

// ---- fallback: R3 direct f32 gather ----
__global__ __launch_bounds__(256) void trilerp_f32_kernel(
    const float* __restrict__ pos,
    const f32x4* __restrict__ feats4,
    f32x4* __restrict__ out4,
    int n)
{
    const int tid = blockIdx.x * 256 + threadIdx.x;
    const int pt  = tid >> 4;
    if (pt >= n) return;
    const int sub = tid & 15;

    const float px = pos[pt * 3], py = pos[pt * 3 + 1], pz = pos[pt * 3 + 2];
    int ci, cj, ck;
    cell_of(px, py, pz, ci, cj, ck);

    const float INV_GS = 64.0f / 2.1f;
    float vx0 = ((float)ci       * 0.015625f - 0.5f) * 2.1f;
    float vx1 = ((float)(ci + 1) * 0.015625f - 0.5f) * 2.1f;
    float vy0 = ((float)cj       * 0.015625f - 0.5f) * 2.1f;
    float vy1 = ((float)(cj + 1) * 0.015625f - 0.5f) * 2.1f;
    float vz0 = ((float)ck       * 0.015625f - 0.5f) * 2.1f;
    float vz1 = ((float)(ck + 1) * 0.015625f - 0.5f) * 2.1f;

    float wx1 = fabsf(px - vx0) * INV_GS;
    float wx0 = fabsf(px - vx1) * INV_GS;
    float wy1 = fabsf(py - vy0) * INV_GS;
    float wy0 = fabsf(py - vy1) * INV_GS;
    float wz1 = fabsf(pz - vz0) * INV_GS;
    float wz0 = fabsf(pz - vz1) * INV_GS;

    const int RS = 16, SY = GRID_R1 * RS, SX = GRID_R1 * GRID_R1 * RS;
    int base = ((ci * GRID_R1 + cj) * GRID_R1 + ck) * RS + sub;

    f32x4 f000 = feats4[base];
    f32x4 f001 = feats4[base + RS];
    f32x4 f010 = feats4[base + SY];
    f32x4 f011 = feats4[base + SY + RS];
    f32x4 f100 = feats4[base + SX];
    f32x4 f101 = feats4[base + SX + RS];
    f32x4 f110 = feats4[base + SX + SY];
    f32x4 f111 = feats4[base + SX + SY + RS];

    float w000 = wx0 * wy0 * wz0, w001 = wx0 * wy0 * wz1;
    float w010 = wx0 * wy1 * wz0, w011 = wx0 * wy1 * wz1;
    float w100 = wx1 * wy0 * wz0, w101 = wx1 * wy0 * wz1;
    float w110 = wx1 * wy1 * wz0, w111 = wx1 * wy1 * wz1;

    f32x4 acc = f000 * w000 + f001 * w001 + f010 * w010 + f011 * w011
              + f100 * w100 + f101 * w101 + f110 * w110 + f111 * w111;

    __builtin_nontemporal_store(acc, &out4[pt * 16 + sub]);
}

extern "C" void kernel_launch(void* const* d_in, const int* in_sizes, int n_in,
                              void* d_out, int out_size, void* d_ws, size_t ws_size,
                              hipStream_t stream) {
    const float* pos   = (const float*)d_in[0];
    const float* feats = (const float*)d_in[1];
    f32x4* out4 = (f32x4*)d_out;

    const int n  = in_sizes[0] / 3;                 // 500000
    const int n8 = (int)(FEAT_ELEMS / 8);           // 2,197,000

    const size_t featBytes = FEAT_ELEMS * sizeof(_Float16);      // 35.15 MB
    const size_t offF = 0;
    const size_t offR = (featBytes + 127) & ~(size_t)127;        // records
    const size_t offH = offR + (size_t)n * 16;                   // hist
    const size_t offC = offH + (size_t)REPS * NBINS * sizeof(int);
    const size_t needSorted = offC + (size_t)REPS * NBINS * sizeof(int);

    if (ws_size >= needSorted) {
        char* ws = (char*)d_ws;
        f16x8* feats16 = (f16x8*)(ws + offF);
        f32x4* records = (f32x4*)(ws + offR);
        int*   hist    = (int*)(ws + offH);
        int*   cursor  = (int*)(ws + offC);

        hipMemsetAsync(hist, 0, (size_t)REPS * NBINS * sizeof(int), stream);

        const int k1_blocks = (n8 + 255) / 256;
        convert_hist_kernel<<<k1_blocks, 256, 0, stream>>>(
            (const f32x4*)feats, feats16, pos, hist, n8, n);

        scan_kernel<<<1, NBINS, 0, stream>>>(hist, cursor);

        scatter_kernel<<<(n + 255) / 256, 256, 0, stream>>>(
            pos, cursor, records, n);

        const int nwg = (n + 31) / 32;
        trilerp_sorted_kernel<<<nwg, 256, 0, stream>>>(
            records, feats16, out4, n, nwg);
    } else if (ws_size >= featBytes) {
        f16x8* feats16 = (f16x8*)d_ws;
        convert_hist_kernel<<<(n8 + 255) / 256, 256, 0, stream>>>(
            (const f32x4*)feats, feats16, nullptr, nullptr, n8, 0);
        const long long total = (long long)n * 8;
        trilerp_f16_kernel<<<(int)((total + 255) / 256), 256, 0, stream>>>(
            pos, feats16, out4, n);
    } else {
        const long long total = (long long)n * 16;
        trilerp_f32_kernel<<<(int)((total + 255) / 256), 256, 0, stream>>>(
            pos, (const f32x4*)feats, out4, n);
    }
}

// Round 7
// 112.744 us; speedup vs baseline: 3.4330x; 1.1304x over previous
//
#include <hip/hip_runtime.h>
#include <hip/hip_fp16.h>

// Trilinear feature interpolation on a regular 65^3 vertex grid.
// R=64, SCALE=1.05, C=64, N=500000.
//
// R7: revert the counting sort (R6: 35us preprocessing bought only 15us in
// the gather -> net loss). Keep R4's convert(f32->f16) + gather pipeline and
// attack the measured limiter instead: the gather is latency/ILP-bound
// (78-93us while moving only ~2-4 TB/s, VALUBusy ~25%). Each thread now
// processes TWO points -> 16 outstanding 16B feat loads per thread.

#define GRID_R     64
#define GRID_R1    65
#define NCHAN      64
#define NVERT      (GRID_R1 * GRID_R1 * GRID_R1)    // 274625
#define FEAT_ELEMS ((size_t)NVERT * NCHAN)          // 17,576,000 floats

typedef float    f32x4 __attribute__((ext_vector_type(4)));
typedef _Float16 f16x8 __attribute__((ext_vector_type(8)));

__device__ __forceinline__ void cell_of(float px, float py, float pz,
                                        int& ci, int& cj, int& ck) {
    float x = (px / 2.1f + 0.5f) * 64.0f;
    float y = (py / 2.1f + 0.5f) * 64.0f;
    float z = (pz / 2.1f + 0.5f) * 64.0f;
    x = fminf(fmaxf(x, 0.0f), 64.0f);
    y = fminf(fmaxf(y, 0.0f), 64.0f);
    z = fminf(fmaxf(z, 0.0f), 64.0f);
    ci = min((int)x, GRID_R - 1);
    cj = min((int)y, GRID_R - 1);
    ck = min((int)z, GRID_R - 1);
}

// Weights (corner order c = 4dx+2dy+dz, flipped-vertex convention) + row base.
__device__ __forceinline__ void setup_point(float px, float py, float pz, int sub,
                                            int& base, float (&w)[8]) {
    int ci, cj, ck;
    cell_of(px, py, pz, ci, cj, ck);

    const float INV_GS = 64.0f / 2.1f;
    float vx0 = ((float)ci       * 0.015625f - 0.5f) * 2.1f;
    float vx1 = ((float)(ci + 1) * 0.015625f - 0.5f) * 2.1f;
    float vy0 = ((float)cj       * 0.015625f - 0.5f) * 2.1f;
    float vy1 = ((float)(cj + 1) * 0.015625f - 0.5f) * 2.1f;
    float vz0 = ((float)ck       * 0.015625f - 0.5f) * 2.1f;
    float vz1 = ((float)(ck + 1) * 0.015625f - 0.5f) * 2.1f;

    // Corner (dx,dy,dz) is weighted by distance to the OPPOSITE vertex.
    float wx1 = fabsf(px - vx0) * INV_GS;
    float wx0 = fabsf(px - vx1) * INV_GS;
    float wy1 = fabsf(py - vy0) * INV_GS;
    float wy0 = fabsf(py - vy1) * INV_GS;
    float wz1 = fabsf(pz - vz0) * INV_GS;
    float wz0 = fabsf(pz - vz1) * INV_GS;

    w[0] = wx0 * wy0 * wz0;  w[1] = wx0 * wy0 * wz1;
    w[2] = wx0 * wy1 * wz0;  w[3] = wx0 * wy1 * wz1;
    w[4] = wx1 * wy0 * wz0;  w[5] = wx1 * wy0 * wz1;
    w[6] = wx1 * wy1 * wz0;  w[7] = wx1 * wy1 * wz1;

    base = ((ci * GRID_R1 + cj) * GRID_R1 + ck) * (NCHAN / 8) + sub;
}

// ---- pass 1: feats f32 -> f16 (streaming) ----
__global__ __launch_bounds__(256) void convert_kernel(
    const f32x4* __restrict__ in,
    f16x8* __restrict__ out,
    int n8)
{
    int i = blockIdx.x * 256 + threadIdx.x;
    if (i >= n8) return;
    f32x4 a = __builtin_nontemporal_load(&in[2 * i]);
    f32x4 b = __builtin_nontemporal_load(&in[2 * i + 1]);
    f16x8 h;
    h[0] = (_Float16)a.x; h[1] = (_Float16)a.y;
    h[2] = (_Float16)a.z; h[3] = (_Float16)a.w;
    h[4] = (_Float16)b.x; h[5] = (_Float16)b.y;
    h[6] = (_Float16)b.z; h[7] = (_Float16)b.w;
    __builtin_nontemporal_store(h, &out[i]);
}

// ---- pass 2: trilerp gather, 2 points per thread (16 loads in flight) ----
__global__ __launch_bounds__(256) void trilerp_f16x2_kernel(
    const float* __restrict__ pos,    // [n,3]
    const f16x8* __restrict__ feats,  // [65^3, 8] f16x8 (64 ch per row)
    f32x4* __restrict__ out4,         // [n,16] f32x4
    int n)
{
    const int g   = threadIdx.x >> 3;              // 0..31 point-group in block
    const int sub = threadIdx.x & 7;               // which f16x8 of the row
    const int p0  = blockIdx.x * 64 + g;           // block covers 64 points
    const int p1t = blockIdx.x * 64 + 32 + g;
    if (p0 >= n) return;
    const bool do1 = (p1t < n);
    const int p1 = do1 ? p1t : p0;                 // clamp (stores guarded)

    // 8 lanes broadcast-read the same 3 floats per point.
    float px0 = pos[p0 * 3], py0 = pos[p0 * 3 + 1], pz0 = pos[p0 * 3 + 2];
    float px1 = pos[p1 * 3], py1 = pos[p1 * 3 + 1], pz1 = pos[p1 * 3 + 2];

    int b0, b1;
    float w0[8], w1[8];
    setup_point(px0, py0, pz0, sub, b0, w0);
    setup_point(px1, py1, pz1, sub, b1, w1);

    const int RS = NCHAN / 8;
    const int SY = GRID_R1 * RS;
    const int SX = GRID_R1 * GRID_R1 * RS;

    // Issue all 16 gathers up front (independent -> deep MLP).
    f16x8 F0[8], F1[8];
    F0[0] = feats[b0];                F0[1] = feats[b0 + RS];
    F0[2] = feats[b0 + SY];           F0[3] = feats[b0 + SY + RS];
    F0[4] = feats[b0 + SX];           F0[5] = feats[b0 + SX + RS];
    F0[6] = feats[b0 + SX + SY];      F0[7] = feats[b0 + SX + SY + RS];
    F1[0] = feats[b1];                F1[1] = feats[b1 + RS];
    F1[2] = feats[b1 + SY];           F1[3] = feats[b1 + SY + RS];
    F1[4] = feats[b1 + SX];           F1[5] = feats[b1 + SX + RS];
    F1[6] = feats[b1 + SX + SY];      F1[7] = feats[b1 + SX + SY + RS];

    f32x4 a0 = {0.f,0.f,0.f,0.f}, c0 = {0.f,0.f,0.f,0.f};
    f32x4 a1 = {0.f,0.f,0.f,0.f}, c1 = {0.f,0.f,0.f,0.f};
#pragma unroll
    for (int c = 0; c < 8; ++c) {
        float w = w0[c];
        a0.x += (float)F0[c][0] * w; a0.y += (float)F0[c][1] * w;
        a0.z += (float)F0[c][2] * w; a0.w += (float)F0[c][3] * w;
        c0.x += (float)F0[c][4] * w; c0.y += (float)F0[c][5] * w;
        c0.z += (float)F0[c][6] * w; c0.w += (float)F0[c][7] * w;
    }
#pragma unroll
    for (int c = 0; c < 8; ++c) {
        float w = w1[c];
        a1.x += (float)F1[c][0] * w; a1.y += (float)F1[c][1] * w;
        a1.z += (float)F1[c][2] * w; a1.w += (float)F1[c][3] * w;
        c1.x += (float)F1[c][4] * w; c1.y += (float)F1[c][5] * w;
        c1.z += (float)F1[c][6] * w; c1.w += (float)F1[c][7] * w;
    }

    // Write-once output: nontemporal so it doesn't evict the feats table.
    __builtin_nontemporal_store(a0, &out4[p0 * 16 + sub * 2]);
    __builtin_nontemporal_store(c0, &out4[p0 * 16 + sub * 2 + 1]);
    if (do1) {
        __builtin_nontemporal_store(a1, &out4[p1 * 16 + sub * 2]);
        __builtin_nontemporal_store(c1, &out4[p1 * 16 + sub * 2 + 1]);
    }
}

// ---- fallback: direct f32 gather (if d_ws too small for the f16 table) ----
__global__ __launch_bounds__(256) void trilerp_f32_kernel(
    const float* __restrict__ pos,
    const f32x4* __restrict__ feats4,
    f32x4* __restrict__ out4,
    int n)
{
    const int tid = blockIdx.x * 256 + threadIdx.x;
    const int pt  = tid >> 4;
    if (pt >= n) return;
    const int sub = tid & 15;

    const float px = pos[pt * 3], py = pos[pt * 3 + 1], pz = pos[pt * 3 + 2];
    int b;
    float w[8];
    // f32 table: row = 16 f32x4 units
    {
        int ci, cj, ck;
        cell_of(px, py, pz, ci, cj, ck);
        const float INV_GS = 64.0f / 2.1f;
        float vx0 = ((float)ci       * 0.015625f - 0.5f) * 2.1f;
        float vx1 = ((float)(ci + 1) * 0.015625f - 0.5f) * 2.1f;
        float vy0 = ((float)cj       * 0.015625f - 0.5f) * 2.1f;
        float vy1 = ((float)(cj + 1) * 0.015625f - 0.5f) * 2.1f;
        float vz0 = ((float)ck       * 0.015625f - 0.5f) * 2.1f;
        float vz1 = ((float)(ck + 1) * 0.015625f - 0.5f) * 2.1f;
        float wx1 = fabsf(px - vx0) * INV_GS, wx0 = fabsf(px - vx1) * INV_GS;
        float wy1 = fabsf(py - vy0) * INV_GS, wy0 = fabsf(py - vy1) * INV_GS;
        float wz1 = fabsf(pz - vz0) * INV_GS, wz0 = fabsf(pz - vz1) * INV_GS;
        w[0] = wx0*wy0*wz0; w[1] = wx0*wy0*wz1; w[2] = wx0*wy1*wz0; w[3] = wx0*wy1*wz1;
        w[4] = wx1*wy0*wz0; w[5] = wx1*wy0*wz1; w[6] = wx1*wy1*wz0; w[7] = wx1*wy1*wz1;
        b = ((ci * GRID_R1 + cj) * GRID_R1 + ck) * 16 + sub;
    }
    const int RS = 16, SY = GRID_R1 * RS, SX = GRID_R1 * GRID_R1 * RS;
    const int off[8] = {0, RS, SY, SY + RS, SX, SX + RS, SX + SY, SX + SY + RS};

    f32x4 acc = {0.f, 0.f, 0.f, 0.f};
#pragma unroll
    for (int c = 0; c < 8; ++c) acc += feats4[b + off[c]] * w[c];

    __builtin_nontemporal_store(acc, &out4[pt * 16 + sub]);
}

extern "C" void kernel_launch(void* const* d_in, const int* in_sizes, int n_in,
                              void* d_out, int out_size, void* d_ws, size_t ws_size,
                              hipStream_t stream) {
    const float* pos   = (const float*)d_in[0];
    const float* feats = (const float*)d_in[1];
    // d_in[2] (vertices) and d_in[3] (grid_indices) recomputed analytically.
    f32x4* out4 = (f32x4*)d_out;

    const int n  = in_sizes[0] / 3;                 // 500000
    const int n8 = (int)(FEAT_ELEMS / 8);           // 2,197,000
    const size_t featBytes = FEAT_ELEMS * sizeof(_Float16);  // 35.15 MB

    if (ws_size >= featBytes) {
        f16x8* feats16 = (f16x8*)d_ws;
        convert_kernel<<<(n8 + 255) / 256, 256, 0, stream>>>(
            (const f32x4*)feats, feats16, n8);
        const int blocks = (n + 63) / 64;           // 64 points per block
        trilerp_f16x2_kernel<<<blocks, 256, 0, stream>>>(
            pos, feats16, out4, n);
    } else {
        const long long total = (long long)n * 16;
        trilerp_f32_kernel<<<(int)((total + 255) / 256), 256, 0, stream>>>(
            pos, (const f32x4*)feats, out4, n);
    }
}